// Round 5
// baseline (232.611 us; speedup 1.0000x reference)
//
#include <hip/hip_runtime.h>
#include <hip/hip_bf16.h>

typedef __attribute__((ext_vector_type(8))) short bfrag;   // 8 bf16 (A/B operand)
typedef __attribute__((ext_vector_type(4))) float facc;    // 4 f32  (C/D operand)

static __device__ __forceinline__ float bf2f_lo(unsigned int u) {
    return __uint_as_float(u << 16);
}
static __device__ __forceinline__ float bf2f_hi(unsigned int u) {
    return __uint_as_float(u & 0xffff0000u);
}
static __device__ __forceinline__ unsigned short f2bf(float f) {
    __hip_bfloat16 b = __float2bfloat16(f);  // RNE
    return *reinterpret_cast<unsigned short*>(&b);
}

// ---------------------------------------------------------------------------
// Merged precompute: Y[row][0:128] = h@W1[0:128], Y[row][128:256] = h@W1[128:256]
// for BOTH node tables in one launch (grid-stride over user tiles then item).
// MFMA 16x16x32 bf16; wave w owns cols [w*64, w*64+64); W1 frags in registers.
// D layout (verified): col = lane&15, row = (lane>>4)*4 + reg.
// ---------------------------------------------------------------------------
extern "C" __global__ __launch_bounds__(256)
void precompute_mfma(const float* __restrict__ hu, int nu,
                     const float* __restrict__ hi, int ni,
                     const float* __restrict__ W1,
                     unsigned short* __restrict__ Yu,
                     unsigned short* __restrict__ Yi)
{
    const int tid = threadIdx.x, wave = tid >> 6, lane = tid & 63;
    const int g = lane >> 4, e16 = lane & 15;
    const int c0 = wave * 64;

    bfrag bfr[4][4];
    #pragma unroll
    for (int nt = 0; nt < 4; ++nt) {
        const int j = c0 + nt * 16 + e16;
        #pragma unroll
        for (int kk = 0; kk < 4; ++kk) {
            bfrag v;
            #pragma unroll
            for (int i = 0; i < 8; ++i) {
                int k = kk * 32 + g * 8 + i;
                float w = (j < 128) ? W1[(size_t)k * 128 + j]
                                    : W1[(size_t)(128 + k) * 128 + (j - 128)];
                v[i] = (short)f2bf(w);
            }
            bfr[nt][kk] = v;
        }
    }

    const int tu = (nu + 15) >> 4, ti = (ni + 15) >> 4, tt = tu + ti;
    for (int tile = blockIdx.x; tile < tt; tile += gridDim.x) {
        const float* h; unsigned short* Y; int n, node0;
        if (tile < tu) { h = hu; Y = Yu; n = nu; node0 = tile * 16; }
        else           { h = hi; Y = Yi; n = ni; node0 = (tile - tu) * 16; }

        int arow = node0 + e16; if (arow >= n) arow = n - 1;
        facc acc[4] = {{0,0,0,0},{0,0,0,0},{0,0,0,0},{0,0,0,0}};
        #pragma unroll
        for (int kk = 0; kk < 4; ++kk) {
            const float* ap = h + (size_t)arow * 128 + kk * 32 + g * 8;
            float4 a0 = *(const float4*)ap;
            float4 a1v = *(const float4*)(ap + 4);
            bfrag af;
            af[0] = (short)f2bf(a0.x);  af[1] = (short)f2bf(a0.y);
            af[2] = (short)f2bf(a0.z);  af[3] = (short)f2bf(a0.w);
            af[4] = (short)f2bf(a1v.x); af[5] = (short)f2bf(a1v.y);
            af[6] = (short)f2bf(a1v.z); af[7] = (short)f2bf(a1v.w);
            #pragma unroll
            for (int nt = 0; nt < 4; ++nt)
                acc[nt] = __builtin_amdgcn_mfma_f32_16x16x32_bf16(af, bfr[nt][kk], acc[nt], 0, 0, 0);
        }
        #pragma unroll
        for (int nt = 0; nt < 4; ++nt)
            #pragma unroll
            for (int r = 0; r < 4; ++r) {
                int row = node0 + g * 4 + r;
                if (row < n)
                    Y[(size_t)row * 256 + c0 + nt * 16 + e16] = f2bf(acc[nt][r]);
            }
    }
}

// ---------------------------------------------------------------------------
// Edge phase: 16 edges/wave/iter, edges-as-columns MFMA, software-pipelined.
// Prefetch state in NAMED uint4 registers (no arrays, no lambdas -> no
// address-taken -> no scratch). D1 transpose buffer bf16 (16 KB/block),
// XOR-swizzled at 16B granule. Round-5: grid 2048 (TLP was the limiter —
// VGPR=84 allows 6 waves/SIMD but grid=1024 capped at 4 blocks/CU).
// ---------------------------------------------------------------------------
extern "C" __global__ __launch_bounds__(256, 3)
void edge_mfma(const unsigned short* __restrict__ Yu,
               const unsigned short* __restrict__ Yi,
               const float* __restrict__ ef_orders,
               const float* __restrict__ ef_rev,
               const int* __restrict__ src_orders,
               const int* __restrict__ dst_orders,
               const int* __restrict__ src_rev,
               const int* __restrict__ dst_rev,
               const float* __restrict__ W1,
               const float* __restrict__ b1,
               const float* __restrict__ W2,
               const float* __restrict__ b2,
               const float* __restrict__ W3,
               const float* __restrict__ b3,
               float* __restrict__ out, int E)
{
    __shared__ __align__(16) unsigned short d1_lds[4][16][128];  // 16 KB
    const int tid = threadIdx.x, wave = tid >> 6, lane = tid & 63;
    const int g = lane >> 4, e16 = lane & 15;
    unsigned short (*my_lds)[128] = d1_lds[wave];
    const int swzb = (e16 & 7) << 3;   // bf16-unit XOR, 16B granule

    // A frags for ef GEMM: W1c^T tiles; K-slot 16 carries b1 (B supplies 1.0)
    bfrag a1[8];
    #pragma unroll
    for (int t = 0; t < 8; ++t) {
        bfrag v;
        #pragma unroll
        for (int i = 0; i < 8; ++i) {
            const int k = g * 8 + i;
            unsigned short s16 = 0;
            if (k < 16)       s16 = f2bf(W1[(size_t)(256 + k) * 128 + t * 16 + e16]);
            else if (k == 16) s16 = f2bf(b1[t * 16 + e16]);
            v[i] = (short)s16;
        }
        a1[t] = v;
    }
    // W2^T A-frags for the second GEMM
    bfrag w2t[2][4];
    #pragma unroll
    for (int nt = 0; nt < 2; ++nt)
        #pragma unroll
        for (int kk = 0; kk < 4; ++kk) {
            bfrag v;
            #pragma unroll
            for (int i = 0; i < 8; ++i) {
                int k = kk * 32 + g * 8 + i;
                v[i] = (short)f2bf(W2[(size_t)k * 32 + nt * 16 + e16]);
            }
            w2t[nt][kk] = v;
        }
    float b2v[2][4], w3v[2][4];
    #pragma unroll
    for (int nt = 0; nt < 2; ++nt)
        #pragma unroll
        for (int r = 0; r < 4; ++r) {
            b2v[nt][r] = b2[nt * 16 + g * 4 + r];
            w3v[nt][r] = W3[nt * 16 + g * 4 + r];
        }
    const float b3s = b3[0];

    const long twoE = 2L * E;
    const int nbatch = (int)((twoE + 15) >> 4);
    const int stride = gridDim.x * 4;
    int b = blockIdx.x * 4 + wave;

    // pipeline state — all named scalars/vectors (register-resident)
    int s_pf = 0, d_pf = 0;
    uint4 ys0, ys1, ys2, ys3, yd0, yd1, yd2, yd3;
    float4 ef0 = make_float4(0, 0, 0, 0), ef1 = make_float4(0, 0, 0, 0);

#define LOADIDX(BB) do {                                                      \
        long el_ = ((long)(BB) << 4) + e16;                                   \
        if (el_ >= twoE) el_ = twoE - 1;                                      \
        const bool rv_ = el_ >= E;                                            \
        const int ee_ = (int)(rv_ ? el_ - E : el_);                           \
        s_pf = (rv_ ? src_rev : src_orders)[ee_];                             \
        d_pf = (rv_ ? dst_rev : dst_orders)[ee_];                             \
    } while (0)

#define GATHER(BB) do {                                                       \
        long el_ = ((long)(BB) << 4) + e16;                                   \
        if (el_ >= twoE) el_ = twoE - 1;                                      \
        const bool rv_ = el_ >= E;                                            \
        const int ee_ = (int)(rv_ ? el_ - E : el_);                           \
        const unsigned short* ps_ = (rv_ ? Yi : Yu) + (size_t)s_pf * 256 + g * 8; \
        const unsigned short* pd_ = (rv_ ? Yu : Yi) + (size_t)d_pf * 256 + 128 + g * 8; \
        ys0 = *(const uint4*)(ps_);      ys1 = *(const uint4*)(ps_ + 32);     \
        ys2 = *(const uint4*)(ps_ + 64); ys3 = *(const uint4*)(ps_ + 96);     \
        yd0 = *(const uint4*)(pd_);      yd1 = *(const uint4*)(pd_ + 32);     \
        yd2 = *(const uint4*)(pd_ + 64); yd3 = *(const uint4*)(pd_ + 96);     \
        if (g < 2) {                                                          \
            const float* ep_ = (rv_ ? ef_rev : ef_orders) + (size_t)ee_ * 16 + g * 8; \
            ef0 = *(const float4*)ep_;  ef1 = *(const float4*)(ep_ + 4);      \
        }                                                                     \
    } while (0)

#define PSTEP(KK, YSU, YDU) do {                                              \
        uint4 wv = *(const uint4*)&my_lds[e16][((KK) * 32 + g * 8) ^ swzb];   \
        float p0 = bf2f_lo(YSU.x) + bf2f_lo(YDU.x) + bf2f_lo(wv.x);           \
        float p1 = bf2f_hi(YSU.x) + bf2f_hi(YDU.x) + bf2f_hi(wv.x);           \
        float p2 = bf2f_lo(YSU.y) + bf2f_lo(YDU.y) + bf2f_lo(wv.y);           \
        float p3 = bf2f_hi(YSU.y) + bf2f_hi(YDU.y) + bf2f_hi(wv.y);           \
        float p4 = bf2f_lo(YSU.z) + bf2f_lo(YDU.z) + bf2f_lo(wv.z);           \
        float p5 = bf2f_hi(YSU.z) + bf2f_hi(YDU.z) + bf2f_hi(wv.z);           \
        float p6 = bf2f_lo(YSU.w) + bf2f_lo(YDU.w) + bf2f_lo(wv.w);           \
        float p7 = bf2f_hi(YSU.w) + bf2f_hi(YDU.w) + bf2f_hi(wv.w);           \
        bfrag pa;                                                             \
        pa[0] = (short)f2bf(fmaxf(p0, 0.f)); pa[1] = (short)f2bf(fmaxf(p1, 0.f)); \
        pa[2] = (short)f2bf(fmaxf(p2, 0.f)); pa[3] = (short)f2bf(fmaxf(p3, 0.f)); \
        pa[4] = (short)f2bf(fmaxf(p4, 0.f)); pa[5] = (short)f2bf(fmaxf(p5, 0.f)); \
        pa[6] = (short)f2bf(fmaxf(p6, 0.f)); pa[7] = (short)f2bf(fmaxf(p7, 0.f)); \
        acc2a = __builtin_amdgcn_mfma_f32_16x16x32_bf16(w2t[0][KK], pa, acc2a, 0, 0, 0); \
        acc2b = __builtin_amdgcn_mfma_f32_16x16x32_bf16(w2t[1][KK], pa, acc2b, 0, 0, 0); \
    } while (0)

    if (b < nbatch) {
        LOADIDX(b);
        GATHER(b);
        if (b + stride < nbatch) LOADIDX(b + stride);
    }

    for (; b < nbatch; b += stride) {
        // B frag from prefetched ef (lanes g<2); bias-one at K=16 (g==2)
        bfrag eb;
        #pragma unroll
        for (int i = 0; i < 8; ++i) eb[i] = 0;
        if (g < 2) {
            eb[0] = (short)f2bf(ef0.x); eb[1] = (short)f2bf(ef0.y);
            eb[2] = (short)f2bf(ef0.z); eb[3] = (short)f2bf(ef0.w);
            eb[4] = (short)f2bf(ef1.x); eb[5] = (short)f2bf(ef1.y);
            eb[6] = (short)f2bf(ef1.z); eb[7] = (short)f2bf(ef1.w);
        } else if (g == 2) {
            eb[0] = (short)0x3F80;  // bf16 1.0 -> adds b1[n] to every column
        }

        // D1 = W1c^T @ ef^T + b1 -> bf16 LDS transpose (swizzled)
        #pragma unroll
        for (int t = 0; t < 8; ++t) {
            facc zero = {0, 0, 0, 0};
            facc d1 = __builtin_amdgcn_mfma_f32_16x16x32_bf16(a1[t], eb, zero, 0, 0, 0);
            ushort4 u;
            u.x = f2bf(d1[0]); u.y = f2bf(d1[1]); u.z = f2bf(d1[2]); u.w = f2bf(d1[3]);
            *(ushort4*)&my_lds[e16][(t * 16 + g * 4) ^ swzb] = u;
        }

        // P build + second GEMM (consumes prefetched ys/yd registers)
        facc acc2a = {0, 0, 0, 0}, acc2b = {0, 0, 0, 0};
        PSTEP(0, ys0, yd0);
        PSTEP(1, ys1, yd1);
        PSTEP(2, ys2, yd2);
        PSTEP(3, ys3, yd3);

        // issue next batch's gathers now that ys/yd are consumed;
        // latency hides under tail + next iter's D1 phase + 6-wave/SIMD TLP
        const int bn = b + stride;
        if (bn < nbatch) GATHER(bn);

        // tail: relu(h2+b2) . W3, reduce over g-groups, sigmoid, store
        float h3 = 0.f;
        #pragma unroll
        for (int r = 0; r < 4; ++r) {
            float h2 = fmaxf(acc2a[r] + b2v[0][r], 0.f);
            h3 = fmaf(h2, w3v[0][r], h3);
        }
        #pragma unroll
        for (int r = 0; r < 4; ++r) {
            float h2 = fmaxf(acc2b[r] + b2v[1][r], 0.f);
            h3 = fmaf(h2, w3v[1][r], h3);
        }
        h3 += __shfl_xor(h3, 16, 64);
        h3 += __shfl_xor(h3, 32, 64);
        const long el = ((long)b << 4) + lane;
        if (lane < 16 && el < twoE)
            out[el] = 1.f / (1.f + __expf(-(h3 + b3s)));

        // indices for b + 2*stride (consumed by next iteration's GATHER)
        const int b2n = b + 2 * stride;
        if (b2n < nbatch) LOADIDX(b2n);
    }
#undef LOADIDX
#undef GATHER
#undef PSTEP
}

// ---------------------------------------------------------------------------
// Fallback (ws too small): direct per-edge MLP (round-1 kernel, known good).
// ---------------------------------------------------------------------------
extern "C" __global__ __launch_bounds__(256)
void edge_mlp_direct(const float* __restrict__ h_user,
                     const float* __restrict__ h_item,
                     const float* __restrict__ ef_orders,
                     const float* __restrict__ ef_rev,
                     const int* __restrict__ src_orders,
                     const int* __restrict__ dst_orders,
                     const int* __restrict__ src_rev,
                     const int* __restrict__ dst_rev,
                     const float* __restrict__ W1,
                     const float* __restrict__ b1,
                     const float* __restrict__ W2,
                     const float* __restrict__ b2,
                     const float* __restrict__ W3,
                     const float* __restrict__ b3,
                     float* __restrict__ out, int E)
{
    __shared__ unsigned short W1s[256][128];
    __shared__ float xbuf[4][256];
    __shared__ float h1s[4][128];
    const int tid = threadIdx.x;
    const int wave = tid >> 6, lane = tid & 63;
    const int f0 = 2 * lane;
    const int j2 = lane & 31;
    const int kb = (lane >> 5) * 64;

    for (int i = tid; i < 256 * 128; i += 256)
        W1s[i >> 7][i & 127] = f2bf(W1[i]);
    __syncthreads();

    float w1c0[16], w1c1[16];
    #pragma unroll
    for (int k = 0; k < 16; ++k) {
        w1c0[k] = W1[(256 + k) * 128 + f0];
        w1c1[k] = W1[(256 + k) * 128 + f0 + 1];
    }
    float w2r[64];
    #pragma unroll
    for (int kk = 0; kk < 64; ++kk)
        w2r[kk] = W2[(kb + kk) * 32 + j2];
    const float b10 = b1[f0], b11 = b1[f0 + 1];
    const float b2vv = b2[j2], w3vv = W3[j2], b3v = b3[0];

    const long twoE = 2L * E;
    for (long e = (long)blockIdx.x * 4 + wave; e < twoE; e += (long)gridDim.x * 4) {
        const bool rv = (e >= E);
        const int ee = (int)(rv ? e - E : e);
        const int s = (rv ? src_rev : src_orders)[ee];
        const int d = (rv ? dst_rev : dst_orders)[ee];
        const float* hs = rv ? h_item : h_user;
        const float* hd = rv ? h_user : h_item;
        const float* efp = rv ? ef_rev : ef_orders;

        xbuf[wave][lane]       = hs[(size_t)s * 128 + lane];
        xbuf[wave][64 + lane]  = hs[(size_t)s * 128 + 64 + lane];
        xbuf[wave][128 + lane] = hd[(size_t)d * 128 + lane];
        xbuf[wave][192 + lane] = hd[(size_t)d * 128 + 64 + lane];
        __builtin_amdgcn_wave_barrier();

        float p0 = b10, p1 = b11;
        #pragma unroll 8
        for (int k = 0; k < 256; ++k) {
            float xv = xbuf[wave][k];
            unsigned int w = *(const unsigned int*)&W1s[k][f0];
            p0 = fmaf(xv, bf2f_lo(w), p0);
            p1 = fmaf(xv, bf2f_hi(w), p1);
        }
        const float efv = efp[(size_t)ee * 16 + (lane & 15)];
        #pragma unroll
        for (int k = 0; k < 16; ++k) {
            float ek = __shfl(efv, k, 64);
            p0 = fmaf(ek, w1c0[k], p0);
            p1 = fmaf(ek, w1c1[k], p1);
        }
        p0 = fmaxf(p0, 0.0f);
        p1 = fmaxf(p1, 0.0f);

        *(float2*)&h1s[wave][f0] = make_float2(p0, p1);
        __builtin_amdgcn_wave_barrier();
        float acc = 0.0f;
        #pragma unroll
        for (int q = 0; q < 16; ++q) {
            float4 hv = *(const float4*)&h1s[wave][kb + q * 4];
            acc = fmaf(hv.x, w2r[4 * q + 0], acc);
            acc = fmaf(hv.y, w2r[4 * q + 1], acc);
            acc = fmaf(hv.z, w2r[4 * q + 2], acc);
            acc = fmaf(hv.w, w2r[4 * q + 3], acc);
        }
        __builtin_amdgcn_wave_barrier();
        acc += __shfl_xor(acc, 32, 64);
        float h2 = fmaxf(acc + b2vv, 0.0f);
        float v = h2 * w3vv;
        v += __shfl_xor(v, 16, 64);
        v += __shfl_xor(v, 8, 64);
        v += __shfl_xor(v, 4, 64);
        v += __shfl_xor(v, 2, 64);
        v += __shfl_xor(v, 1, 64);
        if (lane == 0)
            out[e] = 1.0f / (1.0f + __expf(-(v + b3v)));
    }
}

// ---------------------------------------------------------------------------
extern "C" void kernel_launch(void* const* d_in, const int* in_sizes, int n_in,
                              void* d_out, int out_size, void* d_ws, size_t ws_size,
                              hipStream_t stream)
{
    const float* h_user    = (const float*)d_in[0];
    const float* h_item    = (const float*)d_in[1];
    const float* ef_orders = (const float*)d_in[2];
    const float* ef_rev    = (const float*)d_in[3];
    const float* W1        = (const float*)d_in[4];
    const float* b1        = (const float*)d_in[5];
    const float* W2        = (const float*)d_in[6];
    const float* b2        = (const float*)d_in[7];
    const float* W3        = (const float*)d_in[8];
    const float* b3        = (const float*)d_in[9];
    const int* src_orders  = (const int*)d_in[10];
    const int* dst_orders  = (const int*)d_in[11];
    const int* src_rev     = (const int*)d_in[12];
    const int* dst_rev     = (const int*)d_in[13];

    const int n_user = in_sizes[0] / 128;
    const int n_item = in_sizes[1] / 128;
    const int E      = in_sizes[2] / 16;
    float* out = (float*)d_out;

    const size_t need = (size_t)(n_user + n_item) * 256 * sizeof(unsigned short);
    if (ws_size >= need) {
        unsigned short* Yu = (unsigned short*)d_ws;
        unsigned short* Yi = Yu + (size_t)n_user * 256;
        precompute_mfma<<<2048, 256, 0, stream>>>(h_user, n_user, h_item, n_item, W1, Yu, Yi);
        edge_mfma<<<2048, 256, 0, stream>>>(Yu, Yi, ef_orders, ef_rev,
            src_orders, dst_orders, src_rev, dst_rev,
            W1, b1, W2, b2, W3, b3, out, E);
    } else {
        edge_mlp_direct<<<4096, 256, 0, stream>>>(h_user, h_item, ef_orders, ef_rev,
            src_orders, dst_orders, src_rev, dst_rev,
            W1, b1, W2, b2, W3, b3, out, E);
    }
}

// Round 6
// 201.563 us; speedup vs baseline: 1.1540x; 1.1540x over previous
//
#include <hip/hip_runtime.h>
#include <hip/hip_bf16.h>

typedef __attribute__((ext_vector_type(8))) short bfrag;   // 8 bf16 (A/B operand)
typedef __attribute__((ext_vector_type(4))) float facc;    // 4 f32  (C/D operand)
typedef __attribute__((ext_vector_type(2))) float f32x2;

static __device__ __forceinline__ float bf2f_lo(unsigned int u) {
    return __uint_as_float(u << 16);
}
static __device__ __forceinline__ float bf2f_hi(unsigned int u) {
    return __uint_as_float(u & 0xffff0000u);
}
static __device__ __forceinline__ unsigned short f2bf(float f) {
    __hip_bfloat16 b = __float2bfloat16(f);  // RNE
    return *reinterpret_cast<unsigned short*>(&b);
}

// ---------------------------------------------------------------------------
// Merged precompute: Y[row][0:128] = h@W1[0:128], Y[row][128:256] = h@W1[128:256]
// for BOTH node tables, output in OCP fp8-e4m3 (halves the gather table:
// 77->38 MB, so it stays L3-resident under the ef stream + writeback).
// MFMA 16x16x32 bf16; wave w owns cols [w*64, w*64+64); W1 frags in registers.
// D layout (verified): col = lane&15, row = (lane>>4)*4 + reg.
// ---------------------------------------------------------------------------
extern "C" __global__ __launch_bounds__(256)
void precompute_mfma(const float* __restrict__ hu, int nu,
                     const float* __restrict__ hi, int ni,
                     const float* __restrict__ W1,
                     unsigned char* __restrict__ Yu,
                     unsigned char* __restrict__ Yi)
{
    const int tid = threadIdx.x, wave = tid >> 6, lane = tid & 63;
    const int g = lane >> 4, e16 = lane & 15;
    const int c0 = wave * 64;

    bfrag bfr[4][4];
    #pragma unroll
    for (int nt = 0; nt < 4; ++nt) {
        const int j = c0 + nt * 16 + e16;
        #pragma unroll
        for (int kk = 0; kk < 4; ++kk) {
            bfrag v;
            #pragma unroll
            for (int i = 0; i < 8; ++i) {
                int k = kk * 32 + g * 8 + i;
                float w = (j < 128) ? W1[(size_t)k * 128 + j]
                                    : W1[(size_t)(128 + k) * 128 + (j - 128)];
                v[i] = (short)f2bf(w);
            }
            bfr[nt][kk] = v;
        }
    }

    const int tu = (nu + 15) >> 4, ti = (ni + 15) >> 4, tt = tu + ti;
    for (int tile = blockIdx.x; tile < tt; tile += gridDim.x) {
        const float* h; unsigned char* Y; int n, node0;
        if (tile < tu) { h = hu; Y = Yu; n = nu; node0 = tile * 16; }
        else           { h = hi; Y = Yi; n = ni; node0 = (tile - tu) * 16; }

        int arow = node0 + e16; if (arow >= n) arow = n - 1;
        facc acc[4] = {{0,0,0,0},{0,0,0,0},{0,0,0,0},{0,0,0,0}};
        #pragma unroll
        for (int kk = 0; kk < 4; ++kk) {
            const float* ap = h + (size_t)arow * 128 + kk * 32 + g * 8;
            float4 a0 = *(const float4*)ap;
            float4 a1v = *(const float4*)(ap + 4);
            bfrag af;
            af[0] = (short)f2bf(a0.x);  af[1] = (short)f2bf(a0.y);
            af[2] = (short)f2bf(a0.z);  af[3] = (short)f2bf(a0.w);
            af[4] = (short)f2bf(a1v.x); af[5] = (short)f2bf(a1v.y);
            af[6] = (short)f2bf(a1v.z); af[7] = (short)f2bf(a1v.w);
            #pragma unroll
            for (int nt = 0; nt < 4; ++nt)
                acc[nt] = __builtin_amdgcn_mfma_f32_16x16x32_bf16(af, bfr[nt][kk], acc[nt], 0, 0, 0);
        }
        #pragma unroll
        for (int nt = 0; nt < 4; ++nt) {
            // pack 4 accs (4 rows) into one u32 of e4m3 bytes: byte r = acc[r]
            unsigned int pk = __builtin_amdgcn_cvt_pk_fp8_f32(acc[nt][0], acc[nt][1], 0u, false);
            pk = __builtin_amdgcn_cvt_pk_fp8_f32(acc[nt][2], acc[nt][3], pk, true);
            #pragma unroll
            for (int r = 0; r < 4; ++r) {
                int row = node0 + g * 4 + r;
                if (row < n)
                    Y[(size_t)row * 256 + c0 + nt * 16 + e16] =
                        (unsigned char)(pk >> (8 * r));
            }
        }
    }
}

// ---------------------------------------------------------------------------
// Edge phase: 16 edges/wave/iter, edges-as-columns MFMA, software-pipelined.
// Y gathers are fp8-e4m3 (4x8B per lane, hardware v_cvt_pk_f32_fp8 upconvert).
// Prefetch state in NAMED uint2 registers (no arrays -> no scratch).
// D1 transpose buffer bf16 (16 KB/block), XOR-swizzled at 16B granule.
// Grid 1024 (proven best: 2048 thrashed L3 -> more HBM refetch, slower).
// ---------------------------------------------------------------------------
extern "C" __global__ __launch_bounds__(256, 3)
void edge_mfma(const unsigned char* __restrict__ Yu,
               const unsigned char* __restrict__ Yi,
               const float* __restrict__ ef_orders,
               const float* __restrict__ ef_rev,
               const int* __restrict__ src_orders,
               const int* __restrict__ dst_orders,
               const int* __restrict__ src_rev,
               const int* __restrict__ dst_rev,
               const float* __restrict__ W1,
               const float* __restrict__ b1,
               const float* __restrict__ W2,
               const float* __restrict__ b2,
               const float* __restrict__ W3,
               const float* __restrict__ b3,
               float* __restrict__ out, int E)
{
    __shared__ __align__(16) unsigned short d1_lds[4][16][128];  // 16 KB
    const int tid = threadIdx.x, wave = tid >> 6, lane = tid & 63;
    const int g = lane >> 4, e16 = lane & 15;
    unsigned short (*my_lds)[128] = d1_lds[wave];
    const int swzb = (e16 & 7) << 3;   // bf16-unit XOR, 16B granule

    // A frags for ef GEMM: W1c^T tiles; K-slot 16 carries b1 (B supplies 1.0)
    bfrag a1[8];
    #pragma unroll
    for (int t = 0; t < 8; ++t) {
        bfrag v;
        #pragma unroll
        for (int i = 0; i < 8; ++i) {
            const int k = g * 8 + i;
            unsigned short s16 = 0;
            if (k < 16)       s16 = f2bf(W1[(size_t)(256 + k) * 128 + t * 16 + e16]);
            else if (k == 16) s16 = f2bf(b1[t * 16 + e16]);
            v[i] = (short)s16;
        }
        a1[t] = v;
    }
    // W2^T A-frags for the second GEMM
    bfrag w2t[2][4];
    #pragma unroll
    for (int nt = 0; nt < 2; ++nt)
        #pragma unroll
        for (int kk = 0; kk < 4; ++kk) {
            bfrag v;
            #pragma unroll
            for (int i = 0; i < 8; ++i) {
                int k = kk * 32 + g * 8 + i;
                v[i] = (short)f2bf(W2[(size_t)k * 32 + nt * 16 + e16]);
            }
            w2t[nt][kk] = v;
        }
    float b2v[2][4], w3v[2][4];
    #pragma unroll
    for (int nt = 0; nt < 2; ++nt)
        #pragma unroll
        for (int r = 0; r < 4; ++r) {
            b2v[nt][r] = b2[nt * 16 + g * 4 + r];
            w3v[nt][r] = W3[nt * 16 + g * 4 + r];
        }
    const float b3s = b3[0];

    const long twoE = 2L * E;
    const int nbatch = (int)((twoE + 15) >> 4);
    const int stride = gridDim.x * 4;
    int b = blockIdx.x * 4 + wave;

    // pipeline state — all named scalars/vectors (register-resident)
    int s_pf = 0, d_pf = 0;
    uint2 ys0, ys1, ys2, ys3, yd0, yd1, yd2, yd3;
    float4 ef0 = make_float4(0, 0, 0, 0), ef1 = make_float4(0, 0, 0, 0);

#define LOADIDX(BB) do {                                                      \
        long el_ = ((long)(BB) << 4) + e16;                                   \
        if (el_ >= twoE) el_ = twoE - 1;                                      \
        const bool rv_ = el_ >= E;                                            \
        const int ee_ = (int)(rv_ ? el_ - E : el_);                           \
        s_pf = (rv_ ? src_rev : src_orders)[ee_];                             \
        d_pf = (rv_ ? dst_rev : dst_orders)[ee_];                             \
    } while (0)

#define GATHER(BB) do {                                                       \
        long el_ = ((long)(BB) << 4) + e16;                                   \
        if (el_ >= twoE) el_ = twoE - 1;                                      \
        const bool rv_ = el_ >= E;                                            \
        const int ee_ = (int)(rv_ ? el_ - E : el_);                           \
        const unsigned char* ps_ = (rv_ ? Yi : Yu) + (size_t)s_pf * 256 + g * 8; \
        const unsigned char* pd_ = (rv_ ? Yu : Yi) + (size_t)d_pf * 256 + 128 + g * 8; \
        ys0 = *(const uint2*)(ps_);      ys1 = *(const uint2*)(ps_ + 32);     \
        ys2 = *(const uint2*)(ps_ + 64); ys3 = *(const uint2*)(ps_ + 96);     \
        yd0 = *(const uint2*)(pd_);      yd1 = *(const uint2*)(pd_ + 32);     \
        yd2 = *(const uint2*)(pd_ + 64); yd3 = *(const uint2*)(pd_ + 96);     \
        if (g < 2) {                                                          \
            const float* ep_ = (rv_ ? ef_rev : ef_orders) + (size_t)ee_ * 16 + g * 8; \
            ef0 = *(const float4*)ep_;  ef1 = *(const float4*)(ep_ + 4);      \
        }                                                                     \
    } while (0)

#define PSTEP(KK, YSU, YDU) do {                                              \
        uint4 wv = *(const uint4*)&my_lds[e16][((KK) * 32 + g * 8) ^ swzb];   \
        f32x2 s01 = __builtin_amdgcn_cvt_pk_f32_fp8(YSU.x, false);            \
        f32x2 s23 = __builtin_amdgcn_cvt_pk_f32_fp8(YSU.x, true);             \
        f32x2 s45 = __builtin_amdgcn_cvt_pk_f32_fp8(YSU.y, false);            \
        f32x2 s67 = __builtin_amdgcn_cvt_pk_f32_fp8(YSU.y, true);             \
        f32x2 d01 = __builtin_amdgcn_cvt_pk_f32_fp8(YDU.x, false);            \
        f32x2 d23 = __builtin_amdgcn_cvt_pk_f32_fp8(YDU.x, true);             \
        f32x2 d45 = __builtin_amdgcn_cvt_pk_f32_fp8(YDU.y, false);            \
        f32x2 d67 = __builtin_amdgcn_cvt_pk_f32_fp8(YDU.y, true);             \
        float p0 = s01[0] + d01[0] + bf2f_lo(wv.x);                           \
        float p1 = s01[1] + d01[1] + bf2f_hi(wv.x);                           \
        float p2 = s23[0] + d23[0] + bf2f_lo(wv.y);                           \
        float p3 = s23[1] + d23[1] + bf2f_hi(wv.y);                           \
        float p4 = s45[0] + d45[0] + bf2f_lo(wv.z);                           \
        float p5 = s45[1] + d45[1] + bf2f_hi(wv.z);                           \
        float p6 = s67[0] + d67[0] + bf2f_lo(wv.w);                           \
        float p7 = s67[1] + d67[1] + bf2f_hi(wv.w);                           \
        bfrag pa;                                                             \
        pa[0] = (short)f2bf(fmaxf(p0, 0.f)); pa[1] = (short)f2bf(fmaxf(p1, 0.f)); \
        pa[2] = (short)f2bf(fmaxf(p2, 0.f)); pa[3] = (short)f2bf(fmaxf(p3, 0.f)); \
        pa[4] = (short)f2bf(fmaxf(p4, 0.f)); pa[5] = (short)f2bf(fmaxf(p5, 0.f)); \
        pa[6] = (short)f2bf(fmaxf(p6, 0.f)); pa[7] = (short)f2bf(fmaxf(p7, 0.f)); \
        acc2a = __builtin_amdgcn_mfma_f32_16x16x32_bf16(w2t[0][KK], pa, acc2a, 0, 0, 0); \
        acc2b = __builtin_amdgcn_mfma_f32_16x16x32_bf16(w2t[1][KK], pa, acc2b, 0, 0, 0); \
    } while (0)

    if (b < nbatch) {
        LOADIDX(b);
        GATHER(b);
        if (b + stride < nbatch) LOADIDX(b + stride);
    }

    for (; b < nbatch; b += stride) {
        // B frag from prefetched ef (lanes g<2); bias-one at K=16 (g==2)
        bfrag eb;
        #pragma unroll
        for (int i = 0; i < 8; ++i) eb[i] = 0;
        if (g < 2) {
            eb[0] = (short)f2bf(ef0.x); eb[1] = (short)f2bf(ef0.y);
            eb[2] = (short)f2bf(ef0.z); eb[3] = (short)f2bf(ef0.w);
            eb[4] = (short)f2bf(ef1.x); eb[5] = (short)f2bf(ef1.y);
            eb[6] = (short)f2bf(ef1.z); eb[7] = (short)f2bf(ef1.w);
        } else if (g == 2) {
            eb[0] = (short)0x3F80;  // bf16 1.0 -> adds b1[n] to every column
        }

        // D1 = W1c^T @ ef^T + b1 -> bf16 LDS transpose (swizzled)
        #pragma unroll
        for (int t = 0; t < 8; ++t) {
            facc zero = {0, 0, 0, 0};
            facc d1 = __builtin_amdgcn_mfma_f32_16x16x32_bf16(a1[t], eb, zero, 0, 0, 0);
            ushort4 u;
            u.x = f2bf(d1[0]); u.y = f2bf(d1[1]); u.z = f2bf(d1[2]); u.w = f2bf(d1[3]);
            *(ushort4*)&my_lds[e16][(t * 16 + g * 4) ^ swzb] = u;
        }

        // P build + second GEMM (consumes prefetched ys/yd registers)
        facc acc2a = {0, 0, 0, 0}, acc2b = {0, 0, 0, 0};
        PSTEP(0, ys0, yd0);
        PSTEP(1, ys1, yd1);
        PSTEP(2, ys2, yd2);
        PSTEP(3, ys3, yd3);

        // issue next batch's gathers now that ys/yd are consumed;
        // latency hides under tail + next iter's D1 phase + wave TLP
        const int bn = b + stride;
        if (bn < nbatch) GATHER(bn);

        // tail: relu(h2+b2) . W3, reduce over g-groups, sigmoid, store
        float h3 = 0.f;
        #pragma unroll
        for (int r = 0; r < 4; ++r) {
            float h2 = fmaxf(acc2a[r] + b2v[0][r], 0.f);
            h3 = fmaf(h2, w3v[0][r], h3);
        }
        #pragma unroll
        for (int r = 0; r < 4; ++r) {
            float h2 = fmaxf(acc2b[r] + b2v[1][r], 0.f);
            h3 = fmaf(h2, w3v[1][r], h3);
        }
        h3 += __shfl_xor(h3, 16, 64);
        h3 += __shfl_xor(h3, 32, 64);
        const long el = ((long)b << 4) + lane;
        if (lane < 16 && el < twoE)
            out[el] = 1.f / (1.f + __expf(-(h3 + b3s)));

        // indices for b + 2*stride (consumed by next iteration's GATHER)
        const int b2n = b + 2 * stride;
        if (b2n < nbatch) LOADIDX(b2n);
    }
#undef LOADIDX
#undef GATHER
#undef PSTEP
}

// ---------------------------------------------------------------------------
// Fallback (ws too small): direct per-edge MLP (round-1 kernel, known good).
// ---------------------------------------------------------------------------
extern "C" __global__ __launch_bounds__(256)
void edge_mlp_direct(const float* __restrict__ h_user,
                     const float* __restrict__ h_item,
                     const float* __restrict__ ef_orders,
                     const float* __restrict__ ef_rev,
                     const int* __restrict__ src_orders,
                     const int* __restrict__ dst_orders,
                     const int* __restrict__ src_rev,
                     const int* __restrict__ dst_rev,
                     const float* __restrict__ W1,
                     const float* __restrict__ b1,
                     const float* __restrict__ W2,
                     const float* __restrict__ b2,
                     const float* __restrict__ W3,
                     const float* __restrict__ b3,
                     float* __restrict__ out, int E)
{
    __shared__ unsigned short W1s[256][128];
    __shared__ float xbuf[4][256];
    __shared__ float h1s[4][128];
    const int tid = threadIdx.x;
    const int wave = tid >> 6, lane = tid & 63;
    const int f0 = 2 * lane;
    const int j2 = lane & 31;
    const int kb = (lane >> 5) * 64;

    for (int i = tid; i < 256 * 128; i += 256)
        W1s[i >> 7][i & 127] = f2bf(W1[i]);
    __syncthreads();

    float w1c0[16], w1c1[16];
    #pragma unroll
    for (int k = 0; k < 16; ++k) {
        w1c0[k] = W1[(256 + k) * 128 + f0];
        w1c1[k] = W1[(256 + k) * 128 + f0 + 1];
    }
    float w2r[64];
    #pragma unroll
    for (int kk = 0; kk < 64; ++kk)
        w2r[kk] = W2[(kb + kk) * 32 + j2];
    const float b10 = b1[f0], b11 = b1[f0 + 1];
    const float b2vv = b2[j2], w3vv = W3[j2], b3v = b3[0];

    const long twoE = 2L * E;
    for (long e = (long)blockIdx.x * 4 + wave; e < twoE; e += (long)gridDim.x * 4) {
        const bool rv = (e >= E);
        const int ee = (int)(rv ? e - E : e);
        const int s = (rv ? src_rev : src_orders)[ee];
        const int d = (rv ? dst_rev : dst_orders)[ee];
        const float* hs = rv ? h_item : h_user;
        const float* hd = rv ? h_user : h_item;
        const float* efp = rv ? ef_rev : ef_orders;

        xbuf[wave][lane]       = hs[(size_t)s * 128 + lane];
        xbuf[wave][64 + lane]  = hs[(size_t)s * 128 + 64 + lane];
        xbuf[wave][128 + lane] = hd[(size_t)d * 128 + lane];
        xbuf[wave][192 + lane] = hd[(size_t)d * 128 + 64 + lane];
        __builtin_amdgcn_wave_barrier();

        float p0 = b10, p1 = b11;
        #pragma unroll 8
        for (int k = 0; k < 256; ++k) {
            float xv = xbuf[wave][k];
            unsigned int w = *(const unsigned int*)&W1s[k][f0];
            p0 = fmaf(xv, bf2f_lo(w), p0);
            p1 = fmaf(xv, bf2f_hi(w), p1);
        }
        const float efv = efp[(size_t)ee * 16 + (lane & 15)];
        #pragma unroll
        for (int k = 0; k < 16; ++k) {
            float ek = __shfl(efv, k, 64);
            p0 = fmaf(ek, w1c0[k], p0);
            p1 = fmaf(ek, w1c1[k], p1);
        }
        p0 = fmaxf(p0, 0.0f);
        p1 = fmaxf(p1, 0.0f);

        *(float2*)&h1s[wave][f0] = make_float2(p0, p1);
        __builtin_amdgcn_wave_barrier();
        float acc = 0.0f;
        #pragma unroll
        for (int q = 0; q < 16; ++q) {
            float4 hv = *(const float4*)&h1s[wave][kb + q * 4];
            acc = fmaf(hv.x, w2r[4 * q + 0], acc);
            acc = fmaf(hv.y, w2r[4 * q + 1], acc);
            acc = fmaf(hv.z, w2r[4 * q + 2], acc);
            acc = fmaf(hv.w, w2r[4 * q + 3], acc);
        }
        __builtin_amdgcn_wave_barrier();
        acc += __shfl_xor(acc, 32, 64);
        float h2 = fmaxf(acc + b2vv, 0.0f);
        float v = h2 * w3vv;
        v += __shfl_xor(v, 16, 64);
        v += __shfl_xor(v, 8, 64);
        v += __shfl_xor(v, 4, 64);
        v += __shfl_xor(v, 2, 64);
        v += __shfl_xor(v, 1, 64);
        if (lane == 0)
            out[e] = 1.0f / (1.0f + __expf(-(v + b3v)));
    }
}

// ---------------------------------------------------------------------------
extern "C" void kernel_launch(void* const* d_in, const int* in_sizes, int n_in,
                              void* d_out, int out_size, void* d_ws, size_t ws_size,
                              hipStream_t stream)
{
    const float* h_user    = (const float*)d_in[0];
    const float* h_item    = (const float*)d_in[1];
    const float* ef_orders = (const float*)d_in[2];
    const float* ef_rev    = (const float*)d_in[3];
    const float* W1        = (const float*)d_in[4];
    const float* b1        = (const float*)d_in[5];
    const float* W2        = (const float*)d_in[6];
    const float* b2        = (const float*)d_in[7];
    const float* W3        = (const float*)d_in[8];
    const float* b3        = (const float*)d_in[9];
    const int* src_orders  = (const int*)d_in[10];
    const int* dst_orders  = (const int*)d_in[11];
    const int* src_rev     = (const int*)d_in[12];
    const int* dst_rev     = (const int*)d_in[13];

    const int n_user = in_sizes[0] / 128;
    const int n_item = in_sizes[1] / 128;
    const int E      = in_sizes[2] / 16;
    float* out = (float*)d_out;

    const size_t need = (size_t)(n_user + n_item) * 256;  // fp8: 1 B/elem
    if (ws_size >= need) {
        unsigned char* Yu = (unsigned char*)d_ws;
        unsigned char* Yi = Yu + (size_t)n_user * 256;
        precompute_mfma<<<2048, 256, 0, stream>>>(h_user, n_user, h_item, n_item, W1, Yu, Yi);
        edge_mfma<<<1024, 256, 0, stream>>>(Yu, Yi, ef_orders, ef_rev,
            src_orders, dst_orders, src_rev, dst_rev,
            W1, b1, W2, b2, W3, b3, out, E);
    } else {
        edge_mlp_direct<<<4096, 256, 0, stream>>>(h_user, h_item, ef_orders, ef_rev,
            src_orders, dst_orders, src_rev, dst_rev,
            W1, b1, W2, b2, W3, b3, out, E);
    }
}